// Round 5
// baseline (7745.158 us; speedup 1.0000x reference)
//
#include <hip/hip_runtime.h>
#include <hip/hip_fp16.h>

#define V_ 50000
#define E_ 512
#define H_ 1024
#define B_ 128
#define T_ 512
#define NG 4096  // 4*H

typedef _Float16 half8 __attribute__((ext_vector_type(8)));
typedef float f32x4 __attribute__((ext_vector_type(4)));

// ---- workspace layout (bytes) ----
static constexpr size_t WX_OFF   = 0;                                        // 4 MiB: Wx f16 B-frags [ntg 256][kt 16][L 64] half8
static constexpr size_t WH_OFF   = (size_t)4 << 20;                          // 8 MiB: Wh f16 B-frags [hblk 32][nt 8][kt 32][L 64] half8
static constexpr size_t BG_OFF   = (size_t)12 << 20;                         // 16 KiB: bias concat f32 [4096]
static constexpr size_t HBUF_OFF = ((size_t)12 << 20) + ((size_t)64 << 10);  // 512 KiB: h dbuf [2][128][1024] f16
static constexpr size_t BAR_OFF  = ((size_t)12 << 20) + ((size_t)640 << 10); // 2 KiB: flags[group 8][64] u32 epochs
static constexpr size_t XF_OFF   = (size_t)16 << 20;                         // 64 MiB: xf f16 [T][128][512]
static constexpr size_t WS_NEED  = XF_OFF + (size_t)T_ * B_ * E_ * 2;        // 80 MiB

__device__ __forceinline__ float fsigm(float x) { return 1.f / (1.f + __expf(-x)); }
__device__ __forceinline__ float ftanh(float x) {
  float cx = fminf(fmaxf(x, -15.f), 15.f);
  float e = __expf(2.f * cx);
  return (e - 1.f) / (e + 1.f);
}

// swizzled A-frag slot: logical (kt, quad, lo) -> 16B LDS slot.
// reads (kt,quad fixed, lo varies) and writes (lo fixed, kt/quad vary) both
// spread uniformly over the 8 four-bank groups -> conflict-free both ways.
__device__ __forceinline__ int aslot(int kt, int quad, int lo) {
  return (kt << 6) + (quad << 4) + ((lo + kt + 2 * quad) & 15);
}

// ---------------- diag: ws too small — encode ws MiB in out[0] ----------------
__global__ void k_diag(float* __restrict__ out, int n, unsigned wsmb) {
  int i = blockIdx.x * 256 + threadIdx.x;
  if (i < n) out[i] = (i == 0) ? (float)wsmb : 0.1f;
}

// ---------------- prep: frag-layout weights, zero h/flags ----------------
__global__ __launch_bounds__(256) void k_prep(
    const float* __restrict__ Wxi, const float* __restrict__ Wxf,
    const float* __restrict__ Wxo, const float* __restrict__ Wxc,
    const float* __restrict__ Whi, const float* __restrict__ Whf,
    const float* __restrict__ Who, const float* __restrict__ Whc,
    const float* __restrict__ bi, const float* __restrict__ bfp,
    const float* __restrict__ bo, const float* __restrict__ bc,
    char* __restrict__ ws) {
  half8* wx = (half8*)(ws + WX_OFF);
  half8* wh = (half8*)(ws + WH_OFF);
  float* bg = (float*)(ws + BG_OFF);
  half8* hb = (half8*)(ws + HBUF_OFF);
  unsigned* bar = (unsigned*)(ws + BAR_OFF);
  const float* WxA[4] = {Wxi, Wxf, Wxo, Wxc};
  const float* WhA[4] = {Whi, Whf, Who, Whc};
  const float* bA[4]  = {bi, bfp, bo, bc};

  const int ZWX = 256 * 16 * 64;      // 262144 frags
  const int ZWH = 32 * 8 * 32 * 64;   // 524288 frags
  const int ZBG = NG;
  const int ZHB = 2 * B_ * H_ / 8;    // 32768 half8
  const int ZBAR = 512;
  const int total = ZWX + ZWH + ZBG + ZHB + ZBAR;

  for (int it = blockIdx.x * 256 + threadIdx.x; it < total; it += gridDim.x * 256) {
    int i = it;
    if (i < ZWX) {
      // B-frag elem j = Wx_gate[k = kt*32 + quad*8 + j][col]; ntg = g*64 + hblk*2 + ct
      int L = i & 63, kt = (i >> 6) & 15, ntg = i >> 10;
      int gate = ntg >> 6;
      int col = ((ntg & 63) << 4) + (L & 15);
      int k0 = (kt << 5) + ((L >> 4) << 3);
      const float* src = WxA[gate] + (size_t)k0 * H_ + col;
      half8 v;
#pragma unroll
      for (int j = 0; j < 8; j++) v[j] = (_Float16)src[(size_t)j * H_];
      wx[i] = v;
    } else if ((i -= ZWX) < ZWH) {
      // layout [hbk 32][nt 8][kt 32][L 64]; nt = g*2+ct; col = hbk*32 + ct*16 + (L&15)
      int L = i & 63, kt = (i >> 6) & 31, nt = (i >> 11) & 7, hbk = i >> 14;
      int ct = nt & 1, g = nt >> 1;
      int col = (hbk << 5) + (ct << 4) + (L & 15);
      int k0 = (kt << 5) + ((L >> 4) << 3);
      const float* src = WhA[g] + (size_t)k0 * H_ + col;
      half8 v;
#pragma unroll
      for (int j = 0; j < 8; j++) v[j] = (_Float16)src[(size_t)j * H_];
      wh[i] = v;
    } else if ((i -= ZWH) < ZBG) {
      bg[i] = bA[i >> 10][i & 1023];
    } else if ((i -= ZBG) < ZHB) {
      half8 z = {};
      hb[i] = z;
    } else {
      i -= ZHB;
      bar[i] = 0u;
    }
  }
}

// ---------------- embed: xf[t][b][k] = (f16) emb[ids[b][t]][k] ----------------
__global__ __launch_bounds__(256) void k_embed(const int* __restrict__ ids,
                                               const float* __restrict__ emb,
                                               char* __restrict__ ws) {
  half8* xf = (half8*)(ws + XF_OFF);
  const int t = blockIdx.x;
  for (int p = threadIdx.x; p < 128 * 64; p += 256) {
    int b = p >> 6, c8 = p & 63;
    int id = ids[b * T_ + t];
    const float* er = emb + (size_t)id * E_ + (c8 << 3);
    float4 f0 = *(const float4*)er;
    float4 f1 = *(const float4*)(er + 4);
    half8 v;
    v[0] = (_Float16)f0.x; v[1] = (_Float16)f0.y; v[2] = (_Float16)f0.z; v[3] = (_Float16)f0.w;
    v[4] = (_Float16)f1.x; v[5] = (_Float16)f1.y; v[6] = (_Float16)f1.z; v[7] = (_Float16)f1.w;
    xf[((size_t)t * 128 + b) * 64 + c8] = v;
  }
}

// ---------------- fused persistent recurrence + input projection ----------------
// 8 groups x 32 WGs; WG = (group = blk&7 [16 batches], hblk = blk>>3 [32 h-cols x 4 gates]).
// Wave w owns gate g=w (2 col-tiles, full K); Wh+Wx B-frags in registers.
// Per step (2 syncthreads): MFMA acc = Wh·h + Wx·x -> red; sync1;
//   waves 0/1: gates, c-state, packed agent h-stores, s_waitcnt vmcnt(0),
//              per-wave epoch flag (early release), stage xf(t+1);
//   waves 2/3: poll 64 flags, agent-load h(t+1) slab, stage (swizzled);
// syncA. All LDS A-frags use the conflict-free swizzle.
__global__ __launch_bounds__(256, 1) void k_lstm(char* __restrict__ ws) {
  __shared__ half8 hslF[32 * 64];  // 32 KB: h A-frags, swizzled
  __shared__ half8 xfsF[16 * 64];  // 16 KB: xf A-frags, swizzled
  __shared__ f32x4 red[8 * 64];    // 8 KB:  gate C-frag exchange
  const half8* whf = (const half8*)(ws + WH_OFF);
  const half8* wxg = (const half8*)(ws + WX_OFF);
  const float* bgp = (const float*)(ws + BG_OFF);
  _Float16* hbuf = (_Float16*)(ws + HBUF_OFF);
  const half8* xf = (const half8*)(ws + XF_OFF);
  unsigned* bar = (unsigned*)(ws + BAR_OFF);

  const int wg = blockIdx.x;
  const int group = wg & 7;   // batches [group*16, +16)
  const int hblk = wg >> 3;   // h-cols [hblk*32, +32)
  const int hbase = hblk << 5;
  const int tid = threadIdx.x;
  const int L = tid & 63, w = tid >> 6;
  const int lo = L & 15, quad = L >> 4;
  unsigned* flags = bar + group * 64;  // 64 epoch flags per group (2 per WG)

  // B-frags, full-K per wave: Wh (g=w, ct 0..1, kt 0..31), Wx (g=w, ct 0..1, kt 0..15)
  half8 bw[2][32];
#pragma unroll 2
  for (int ct = 0; ct < 2; ct++)
    for (int kt = 0; kt < 32; kt++)
      bw[ct][kt] = whf[((size_t)(hblk * 8 + (w * 2 + ct)) * 32 + kt) * 64 + L];
  half8 wxr[2][16];
#pragma unroll 2
  for (int ct = 0; ct < 2; ct++)
    for (int kt = 0; kt < 16; kt++)
      wxr[ct][kt] = wxg[((size_t)(((w << 6) + (hblk << 1) + ct) * 16 + kt)) * 64 + L];

  float bgr[4] = {};
  f32x4 cst = {};
  if (w < 2) {  // update lanes: ct = w; (b = group*16 + quad*4 + r, col = hbase + w*16 + lo)
#pragma unroll
    for (int g = 0; g < 4; g++) bgr[g] = bgp[g * H_ + hbase + (w << 4) + lo];
  }

  // ---- prologue: waves0/1 stage xf(0); waves2/3 stage h(0) (zeros) ----
  if (w < 2) {
    const half8* xs = xf + (size_t)(group * 16) * 64;
#pragma unroll
    for (int j = 0; j < 8; j++) {
      half8 v = xs[j * 128 + tid];
      int p = j * 128 + tid, row = p >> 6, c8 = p & 63;
      xfsF[aslot(c8 >> 2, c8 & 3, row)] = v;
    }
  } else {
    const int t2 = tid - 128;
    const unsigned long long* hsl =
        (const unsigned long long*)(hbuf + (size_t)(group * 16) * H_);
    unsigned long long hv[32];
#pragma unroll
    for (int j = 0; j < 16; j++) {
      int p = j * 128 + t2;
      hv[2 * j] = __hip_atomic_load(hsl + 2 * p, __ATOMIC_RELAXED, __HIP_MEMORY_SCOPE_AGENT);
      hv[2 * j + 1] =
          __hip_atomic_load(hsl + 2 * p + 1, __ATOMIC_RELAXED, __HIP_MEMORY_SCOPE_AGENT);
    }
#pragma unroll
    for (int j = 0; j < 16; j++) {
      union { unsigned long long u[2]; half8 h; } cv;
      cv.u[0] = hv[2 * j];
      cv.u[1] = hv[2 * j + 1];
      hslF[aslot(t2 >> 2, t2 & 3, j)] = cv.h;
    }
  }
  __syncthreads();  // syncA(0)

  for (int t = 0; t < T_; t++) {
    // waves0/1: issue xf(t+1) loads early (independent of everything)
    half8 xv[8];
    if (w < 2) {
      int ts = t + 1 < T_ ? t + 1 : T_ - 1;
      const half8* xs = xf + ((size_t)ts * 128 + group * 16) * 64;
#pragma unroll
      for (int j = 0; j < 8; j++) xv[j] = xs[j * 128 + tid];
    }

    // MFMA: acc = Wh·h + Wx·x over full K; 4 independent chains
    f32x4 a00 = {}, a01 = {}, a10 = {}, a11 = {};
    const int sb = quad << 4, s0 = lo + 2 * quad;
#pragma unroll
    for (int kt = 0; kt < 32; kt += 2) {
      half8 x0 = hslF[(kt << 6) + sb + ((s0 + kt) & 15)];
      half8 x1 = hslF[((kt + 1) << 6) + sb + ((s0 + kt + 1) & 15)];
      a00 = __builtin_amdgcn_mfma_f32_16x16x32_f16(x0, bw[0][kt], a00, 0, 0, 0);
      a10 = __builtin_amdgcn_mfma_f32_16x16x32_f16(x0, bw[1][kt], a10, 0, 0, 0);
      a01 = __builtin_amdgcn_mfma_f32_16x16x32_f16(x1, bw[0][kt + 1], a01, 0, 0, 0);
      a11 = __builtin_amdgcn_mfma_f32_16x16x32_f16(x1, bw[1][kt + 1], a11, 0, 0, 0);
    }
#pragma unroll
    for (int kt = 0; kt < 16; kt += 2) {
      half8 x0 = xfsF[(kt << 6) + sb + ((s0 + kt) & 15)];
      half8 x1 = xfsF[((kt + 1) << 6) + sb + ((s0 + kt + 1) & 15)];
      a00 = __builtin_amdgcn_mfma_f32_16x16x32_f16(x0, wxr[0][kt], a00, 0, 0, 0);
      a10 = __builtin_amdgcn_mfma_f32_16x16x32_f16(x0, wxr[1][kt], a10, 0, 0, 0);
      a01 = __builtin_amdgcn_mfma_f32_16x16x32_f16(x1, wxr[0][kt + 1], a01, 0, 0, 0);
      a11 = __builtin_amdgcn_mfma_f32_16x16x32_f16(x1, wxr[1][kt + 1], a11, 0, 0, 0);
    }
    red[((w * 2 + 0) << 6) + L] = a00 + a01;
    red[((w * 2 + 1) << 6) + L] = a10 + a11;
    __syncthreads();  // sync1: red ready; hslF/xfsF reads done

    if (w < 2) {
      // gates -> c,h; packed agent stores; early per-wave flag; stage xf(t+1)
      f32x4 gv[4];
#pragma unroll
      for (int g = 0; g < 4; g++) gv[g] = red[((g * 2 + w) << 6) + L];
      _Float16* hw = hbuf + (size_t)((t + 1) & 1) * (B_ * H_);
      float hval[4];
#pragma unroll
      for (int r = 0; r < 4; r++) {
        float gi = gv[0][r] + bgr[0];
        float gf = gv[1][r] + bgr[1];
        float go = gv[2][r] + bgr[2];
        float gc = gv[3][r] + bgr[3];
        float c = fsigm(gf) * cst[r] + fsigm(gi) * ftanh(gc);
        cst[r] = c;
        hval[r] = fsigm(go) * ftanh(c);
      }
#pragma unroll
      for (int r = 0; r < 4; r++) {
        float other = __shfl_xor(hval[r], 1);
        if (!(lo & 1)) {
          union { _Float16 h[2]; unsigned u; } pk;
          pk.h[0] = (_Float16)hval[r];
          pk.h[1] = (_Float16)other;
          __hip_atomic_store(
              (unsigned*)(hw + (size_t)(group * 16 + quad * 4 + r) * H_ + hbase +
                          (w << 4) + lo),
              pk.u, __ATOMIC_RELAXED, __HIP_MEMORY_SCOPE_AGENT);
        }
      }
      // release: own stores drained, then flag (no cache-wide maintenance)
      asm volatile("s_waitcnt vmcnt(0)" ::: "memory");
      if (L == 0)
        __hip_atomic_store(&flags[hblk * 2 + w], (unsigned)(t + 1), __ATOMIC_RELAXED,
                           __HIP_MEMORY_SCOPE_AGENT);
      // stage xf(t+1) (read next step after syncA)
#pragma unroll
      for (int j = 0; j < 8; j++) {
        int p = j * 128 + tid, row = p >> 6, c8 = p & 63;
        xfsF[aslot(c8 >> 2, c8 & 3, row)] = xv[j];
      }
    } else {
      // producer-side prefetch: poll, agent-load h(t+1) slab, stage
      const int t2 = tid - 128;
      const unsigned tgt = (unsigned)(t + 1);
      while (true) {
        unsigned v = __hip_atomic_load(&flags[L], __ATOMIC_RELAXED, __HIP_MEMORY_SCOPE_AGENT);
        if (__all((int)(v >= tgt))) break;
        __builtin_amdgcn_s_sleep(1);
      }
      const unsigned long long* hsl =
          (const unsigned long long*)(hbuf + (size_t)((t + 1) & 1) * (B_ * H_) +
                                      (size_t)(group * 16) * H_);
      unsigned long long hv[32];
#pragma unroll
      for (int j = 0; j < 16; j++) {
        int p = j * 128 + t2;
        hv[2 * j] = __hip_atomic_load(hsl + 2 * p, __ATOMIC_RELAXED, __HIP_MEMORY_SCOPE_AGENT);
        hv[2 * j + 1] =
            __hip_atomic_load(hsl + 2 * p + 1, __ATOMIC_RELAXED, __HIP_MEMORY_SCOPE_AGENT);
      }
#pragma unroll
      for (int j = 0; j < 16; j++) {
        union { unsigned long long u[2]; half8 h; } cv;
        cv.u[0] = hv[2 * j];
        cv.u[1] = hv[2 * j + 1];
        hslF[aslot(t2 >> 2, t2 & 3, j)] = cv.h;
      }
    }
    __syncthreads();  // syncA(t+1): slabs staged; red reusable
  }
}

// ---------------- final: softmax(h @ W_hq + b_q) ----------------
__global__ __launch_bounds__(64) void k_final(const char* __restrict__ ws,
                                              const float* __restrict__ Whq,
                                              const float* __restrict__ bq,
                                              float* __restrict__ out) {
  const int b = blockIdx.x;
  const int l = threadIdx.x;
  const _Float16* h = (const _Float16*)(ws + HBUF_OFF) + (size_t)b * H_;  // h_512 in buf 0
  float lg[10];
#pragma unroll
  for (int o = 0; o < 10; o++) {
    float s = 0.f;
    for (int k = l; k < H_; k += 64) s += (float)h[k] * Whq[k * 10 + o];
#pragma unroll
    for (int d = 32; d > 0; d >>= 1) s += __shfl_down(s, d);
    lg[o] = s;
  }
  if (l == 0) {
    float mx = -1e30f;
    for (int o = 0; o < 10; o++) { lg[o] += bq[o]; mx = fmaxf(mx, lg[o]); }
    float ssum = 0.f, ex[10];
    for (int o = 0; o < 10; o++) { ex[o] = __expf(lg[o] - mx); ssum += ex[o]; }
    for (int o = 0; o < 10; o++) out[b * 10 + o] = ex[o] / ssum;
  }
}

extern "C" void kernel_launch(void* const* d_in, const int* in_sizes, int n_in,
                              void* d_out, int out_size, void* d_ws, size_t ws_size,
                              hipStream_t stream) {
  const int* ids   = (const int*)d_in[0];
  const float* emb = (const float*)d_in[1];
  const float* Wxi = (const float*)d_in[2];
  const float* Whi = (const float*)d_in[3];
  const float* bi  = (const float*)d_in[4];
  const float* Wxf = (const float*)d_in[5];
  const float* Whf = (const float*)d_in[6];
  const float* bfv = (const float*)d_in[7];
  const float* Wxo = (const float*)d_in[8];
  const float* Who = (const float*)d_in[9];
  const float* bo  = (const float*)d_in[10];
  const float* Wxc = (const float*)d_in[11];
  const float* Whc = (const float*)d_in[12];
  const float* bc  = (const float*)d_in[13];
  const float* Whq = (const float*)d_in[14];
  const float* bq  = (const float*)d_in[15];
  float* out = (float*)d_out;
  char* ws = (char*)d_ws;

  if (ws_size < WS_NEED) {
    k_diag<<<(out_size + 255) / 256, 256, 0, stream>>>(out, out_size, (unsigned)(ws_size >> 20));
    return;
  }

  k_prep<<<3217, 256, 0, stream>>>(Wxi, Wxf, Wxo, Wxc, Whi, Whf, Who, Whc, bi, bfv, bo, bc, ws);
  k_embed<<<512, 256, 0, stream>>>(ids, emb, ws);
  k_lstm<<<256, 256, 0, stream>>>(ws);
  k_final<<<128, 64, 0, stream>>>(ws, Whq, bq, out);
}

// Round 6
// 3044.394 us; speedup vs baseline: 2.5441x; 2.5441x over previous
//
#include <hip/hip_runtime.h>
#include <hip/hip_fp16.h>

#define V_ 50000
#define E_ 512
#define H_ 1024
#define B_ 128
#define T_ 512
#define NG 4096  // 4*H

typedef _Float16 half8 __attribute__((ext_vector_type(8)));
typedef float f32x4 __attribute__((ext_vector_type(4)));

// ---- workspace layout (bytes) ----
static constexpr size_t WX_OFF   = 0;                                        // 4 MiB: Wx f16 B-frags [ntg 256][kt 16][L 64] half8
static constexpr size_t WH_OFF   = (size_t)4 << 20;                          // 8 MiB: Wh f16 B-frags [hblk 32][nt 8][kt 32][L 64] half8
static constexpr size_t BG_OFF   = (size_t)12 << 20;                         // 16 KiB: bias concat f32 [4096]
static constexpr size_t HBUF_OFF = ((size_t)12 << 20) + ((size_t)64 << 10);  // 512 KiB: h dbuf [2][128][1024] f16
static constexpr size_t BAR_OFF  = ((size_t)12 << 20) + ((size_t)640 << 10); // 2 KiB: flags[group 8][32] u32 epochs (128B/group)
static constexpr size_t XF_OFF   = (size_t)16 << 20;                         // 64 MiB: xf f16 [T][128][512]
static constexpr size_t WS_NEED  = XF_OFF + (size_t)T_ * B_ * E_ * 2;        // 80 MiB

__device__ __forceinline__ float fsigm(float x) { return 1.f / (1.f + __expf(-x)); }
__device__ __forceinline__ float ftanh(float x) {
  float cx = fminf(fmaxf(x, -15.f), 15.f);
  float e = __expf(2.f * cx);
  return (e - 1.f) / (e + 1.f);
}

// ---------------- diag: ws too small — encode ws MiB in out[0] ----------------
__global__ void k_diag(float* __restrict__ out, int n, unsigned wsmb) {
  int i = blockIdx.x * 256 + threadIdx.x;
  if (i < n) out[i] = (i == 0) ? (float)wsmb : 0.1f;
}

// ---------------- prep: frag-layout weights, zero h/flags ----------------
__global__ __launch_bounds__(256) void k_prep(
    const float* __restrict__ Wxi, const float* __restrict__ Wxf,
    const float* __restrict__ Wxo, const float* __restrict__ Wxc,
    const float* __restrict__ Whi, const float* __restrict__ Whf,
    const float* __restrict__ Who, const float* __restrict__ Whc,
    const float* __restrict__ bi, const float* __restrict__ bfp,
    const float* __restrict__ bo, const float* __restrict__ bc,
    char* __restrict__ ws) {
  half8* wx = (half8*)(ws + WX_OFF);
  half8* wh = (half8*)(ws + WH_OFF);
  float* bg = (float*)(ws + BG_OFF);
  half8* hb = (half8*)(ws + HBUF_OFF);
  unsigned* bar = (unsigned*)(ws + BAR_OFF);
  const float* WxA[4] = {Wxi, Wxf, Wxo, Wxc};
  const float* WhA[4] = {Whi, Whf, Who, Whc};
  const float* bA[4]  = {bi, bfp, bo, bc};

  const int ZWX = 256 * 16 * 64;      // 262144 frags
  const int ZWH = 32 * 8 * 32 * 64;   // 524288 frags
  const int ZBG = NG;
  const int ZHB = 2 * B_ * H_ / 8;    // 32768 half8
  const int ZBAR = 512;
  const int total = ZWX + ZWH + ZBG + ZHB + ZBAR;

  for (int it = blockIdx.x * 256 + threadIdx.x; it < total; it += gridDim.x * 256) {
    int i = it;
    if (i < ZWX) {
      // B-frag elem j = Wx_gate[k = kt*32 + quad*8 + j][col]; ntg = g*64 + hblk*2 + ct
      int L = i & 63, kt = (i >> 6) & 15, ntg = i >> 10;
      int gate = ntg >> 6;
      int col = ((ntg & 63) << 4) + (L & 15);
      int k0 = (kt << 5) + ((L >> 4) << 3);
      const float* src = WxA[gate] + (size_t)k0 * H_ + col;
      half8 v;
#pragma unroll
      for (int j = 0; j < 8; j++) v[j] = (_Float16)src[(size_t)j * H_];
      wx[i] = v;
    } else if ((i -= ZWX) < ZWH) {
      // layout [hbk 32][nt 8][kt 32][L 64]; nt = g*2+ct; col = hbk*32 + ct*16 + (L&15)
      int L = i & 63, kt = (i >> 6) & 31, nt = (i >> 11) & 7, hbk = i >> 14;
      int ct = nt & 1, g = nt >> 1;
      int col = (hbk << 5) + (ct << 4) + (L & 15);
      int k0 = (kt << 5) + ((L >> 4) << 3);
      const float* src = WhA[g] + (size_t)k0 * H_ + col;
      half8 v;
#pragma unroll
      for (int j = 0; j < 8; j++) v[j] = (_Float16)src[(size_t)j * H_];
      wh[i] = v;
    } else if ((i -= ZWH) < ZBG) {
      bg[i] = bA[i >> 10][i & 1023];
    } else if ((i -= ZBG) < ZHB) {
      half8 z = {};
      hb[i] = z;
    } else {
      i -= ZHB;
      bar[i] = 0u;
    }
  }
}

// ---------------- embed: xf[t][b][k] = (f16) emb[ids[b][t]][k] ----------------
__global__ __launch_bounds__(256) void k_embed(const int* __restrict__ ids,
                                               const float* __restrict__ emb,
                                               char* __restrict__ ws) {
  half8* xf = (half8*)(ws + XF_OFF);
  const int t = blockIdx.x;
  for (int p = threadIdx.x; p < 128 * 64; p += 256) {
    int b = p >> 6, c8 = p & 63;
    int id = ids[b * T_ + t];
    const float* er = emb + (size_t)id * E_ + (c8 << 3);
    float4 f0 = *(const float4*)er;
    float4 f1 = *(const float4*)(er + 4);
    half8 v;
    v[0] = (_Float16)f0.x; v[1] = (_Float16)f0.y; v[2] = (_Float16)f0.z; v[3] = (_Float16)f0.w;
    v[4] = (_Float16)f1.x; v[5] = (_Float16)f1.y; v[6] = (_Float16)f1.z; v[7] = (_Float16)f1.w;
    xf[((size_t)t * 128 + b) * 64 + c8] = v;
  }
}

// ---------------- fused persistent recurrence + input projection (R3 structure) ----------------
// 8 groups x 32 WGs; WG = (group = blk&7 [16 batches], hblk = blk>>3 [32 h-cols x 4 gates]).
// Wave w: K-split — Wh K chunk [w*256,+256) (8 k8 x 8 nt MFMAs) PLUS Wx/xf K chunk
// [w*128,+128) (4 kx x 8 nt MFMAs) into the SAME accumulators; cross-wave K-reduce
// via 32KB red. All A-frags loaded straight global->reg (no LDS staging).
// Per step: A loads -> 96 MFMAs -> red -> sync -> waves0/1 reduce+gates+hstage ->
// sync -> tid<128 coalesced 8B agent h-stores -> sync (drain) -> flag -> wave0 poll -> sync.
__global__ __launch_bounds__(256, 1) void k_lstm(char* __restrict__ ws) {
  __shared__ f32x4 red[4][8][64];      // 32 KB
  __shared__ _Float16 hstage[16][32];  // 1 KB
  const half8* whf = (const half8*)(ws + WH_OFF);
  const half8* wxg = (const half8*)(ws + WX_OFF);
  const float* bgp = (const float*)(ws + BG_OFF);
  _Float16* hbuf = (_Float16*)(ws + HBUF_OFF);
  const half8* xf = (const half8*)(ws + XF_OFF);
  unsigned* bar = (unsigned*)(ws + BAR_OFF);

  const int wg = blockIdx.x;
  const int group = wg & 7;   // batches [group*16, +16)
  const int hblk = wg >> 3;   // h-cols [hblk*32, +32) for all 4 gates
  const int hbase = hblk << 5;
  const int tid = threadIdx.x;
  const int L = tid & 63, w = tid >> 6;
  const int lo = L & 15, quad = L >> 4;
  unsigned* flags = bar + group * 32;  // one 128B line per group

  // B-frags (register/AGPR-resident): Wh [nt][k8] for K chunk [w*256,+256)
  half8 bw[8][8];
#pragma unroll
  for (int nt = 0; nt < 8; nt++)
#pragma unroll
    for (int k8 = 0; k8 < 8; k8++)
      bw[nt][k8] = whf[((size_t)(hblk * 8 + nt) * 32 + w * 8 + k8) * 64 + L];
  // Wx [nt][kx] for K chunk [w*128,+128); ntg = g*64 + hblk*2 + ct, nt = g*2+ct
  half8 wxr[8][4];
#pragma unroll
  for (int nt = 0; nt < 8; nt++)
#pragma unroll
    for (int kx = 0; kx < 4; kx++)
      wxr[nt][kx] =
          wxg[(size_t)(((nt >> 1) * 64 + (hblk << 1) + (nt & 1)) * 16 + w * 4 + kx) * 64 + L];

  float bgr[4] = {};
  f32x4 cst = {};
  if (w < 2) {  // update lanes: ct = w; (b = group*16 + quad*4 + r, col = hbase + w*16 + lo)
#pragma unroll
    for (int g = 0; g < 4; g++) bgr[g] = bgp[g * H_ + hbase + (w << 4) + lo];
  }
  __syncthreads();

  for (int t = 0; t < T_; t++) {
    const _Float16* hb = hbuf + (size_t)(t & 1) * (B_ * H_);
    _Float16* hw = hbuf + (size_t)((t + 1) & 1) * (B_ * H_);

    // xf A-frags (normal loads, L2-cacheable): row = group*16+lo, k chunk of this wave
    half8 ax[4];
    {
      const half8* xrow = xf + ((size_t)t * 128 + group * 16 + lo) * 64;
#pragma unroll
      for (int kx = 0; kx < 4; kx++) ax[kx] = xrow[(w * 4 + kx) * 4 + quad];
    }

    // h A-frags via agent-scope loads: A[m=lo][k = (w*8+k8)*32 + quad*8 + j]
    half8 ah[8];
#pragma unroll
    for (int k8 = 0; k8 < 8; k8++) {
      const _Float16* ap =
          hb + (size_t)((group << 4) + lo) * H_ + ((w * 8 + k8) << 5) + (quad << 3);
      union { unsigned long long u[2]; half8 h; } cv;
      cv.u[0] = __hip_atomic_load((const unsigned long long*)ap,
                                  __ATOMIC_RELAXED, __HIP_MEMORY_SCOPE_AGENT);
      cv.u[1] = __hip_atomic_load((const unsigned long long*)(ap + 4),
                                  __ATOMIC_RELAXED, __HIP_MEMORY_SCOPE_AGENT);
      ah[k8] = cv.h;
    }

    // MFMA: acc[nt] = Wh_chunk·h + Wx_chunk·x ; 8 independent chains
    f32x4 acc[8] = {};
#pragma unroll
    for (int k8 = 0; k8 < 8; k8++)
#pragma unroll
      for (int nt = 0; nt < 8; nt++)
        acc[nt] = __builtin_amdgcn_mfma_f32_16x16x32_f16(ah[k8], bw[nt][k8], acc[nt], 0, 0, 0);
#pragma unroll
    for (int kx = 0; kx < 4; kx++)
#pragma unroll
      for (int nt = 0; nt < 8; nt++)
        acc[nt] = __builtin_amdgcn_mfma_f32_16x16x32_f16(ax[kx], wxr[nt][kx], acc[nt], 0, 0, 0);
#pragma unroll
    for (int nt = 0; nt < 8; nt++) red[w][nt][L] = acc[nt];
    __syncthreads();  // sync1: K-partials exchanged

    // update: waves 0/1 (ct = w) reduce partials, gate math, stage h (transpose)
    if (w < 2) {
      f32x4 gv[4];
#pragma unroll
      for (int g = 0; g < 4; g++) {
        f32x4 s = red[0][g * 2 + w][L];
        s += red[1][g * 2 + w][L];
        s += red[2][g * 2 + w][L];
        s += red[3][g * 2 + w][L];
        gv[g] = s;
      }
#pragma unroll
      for (int r = 0; r < 4; r++) {
        float gi = gv[0][r] + bgr[0];
        float gf = gv[1][r] + bgr[1];
        float go = gv[2][r] + bgr[2];
        float gc = gv[3][r] + bgr[3];
        float c = fsigm(gf) * cst[r] + fsigm(gi) * ftanh(gc);
        cst[r] = c;
        hstage[(quad << 2) + r][(w << 4) + lo] = (_Float16)(fsigm(go) * ftanh(c));
      }
    }
    __syncthreads();  // sync2: hstage ready

    // coalesced coherent h stores: one 8B agent store per lane (tid<128)
    if (tid < 128) {
      int bl = tid >> 3, seg = tid & 7;
      union { _Float16 h[4]; unsigned long long u; } cv;
#pragma unroll
      for (int q = 0; q < 4; q++) cv.h[q] = hstage[bl][(seg << 2) + q];
      __hip_atomic_store(
          (unsigned long long*)(hw + (size_t)((group << 4) + bl) * H_ + hbase + (seg << 2)),
          cv.u, __ATOMIC_RELAXED, __HIP_MEMORY_SCOPE_AGENT);
    }
    __syncthreads();  // sync3: barrier drains vmcnt -> stores at coherence point

    // flag + group poll (wave 0 polls one 128B line; others held by sync4)
    if (tid == 0)
      __hip_atomic_store(&flags[hblk], (unsigned)(t + 1), __ATOMIC_RELAXED,
                         __HIP_MEMORY_SCOPE_AGENT);
    if (tid < 64) {
      const unsigned tgt = (unsigned)(t + 1);
      while (true) {
        unsigned v = (tid < 32) ? __hip_atomic_load(&flags[tid], __ATOMIC_RELAXED,
                                                    __HIP_MEMORY_SCOPE_AGENT)
                                : tgt;
        if (__all((int)(v >= tgt))) break;
        __builtin_amdgcn_s_sleep(1);
      }
    }
    __syncthreads();  // sync4: all WGs of group at epoch t+1
  }
}

// ---------------- final: softmax(h @ W_hq + b_q) ----------------
__global__ __launch_bounds__(64) void k_final(const char* __restrict__ ws,
                                              const float* __restrict__ Whq,
                                              const float* __restrict__ bq,
                                              float* __restrict__ out) {
  const int b = blockIdx.x;
  const int l = threadIdx.x;
  const _Float16* h = (const _Float16*)(ws + HBUF_OFF) + (size_t)b * H_;  // h_512 in buf 0
  float lg[10];
#pragma unroll
  for (int o = 0; o < 10; o++) {
    float s = 0.f;
    for (int k = l; k < H_; k += 64) s += (float)h[k] * Whq[k * 10 + o];
#pragma unroll
    for (int d = 32; d > 0; d >>= 1) s += __shfl_down(s, d);
    lg[o] = s;
  }
  if (l == 0) {
    float mx = -1e30f;
    for (int o = 0; o < 10; o++) { lg[o] += bq[o]; mx = fmaxf(mx, lg[o]); }
    float ssum = 0.f, ex[10];
    for (int o = 0; o < 10; o++) { ex[o] = __expf(lg[o] - mx); ssum += ex[o]; }
    for (int o = 0; o < 10; o++) out[b * 10 + o] = ex[o] / ssum;
  }
}

extern "C" void kernel_launch(void* const* d_in, const int* in_sizes, int n_in,
                              void* d_out, int out_size, void* d_ws, size_t ws_size,
                              hipStream_t stream) {
  const int* ids   = (const int*)d_in[0];
  const float* emb = (const float*)d_in[1];
  const float* Wxi = (const float*)d_in[2];
  const float* Whi = (const float*)d_in[3];
  const float* bi  = (const float*)d_in[4];
  const float* Wxf = (const float*)d_in[5];
  const float* Whf = (const float*)d_in[6];
  const float* bfv = (const float*)d_in[7];
  const float* Wxo = (const float*)d_in[8];
  const float* Who = (const float*)d_in[9];
  const float* bo  = (const float*)d_in[10];
  const float* Wxc = (const float*)d_in[11];
  const float* Whc = (const float*)d_in[12];
  const float* bc  = (const float*)d_in[13];
  const float* Whq = (const float*)d_in[14];
  const float* bq  = (const float*)d_in[15];
  float* out = (float*)d_out;
  char* ws = (char*)d_ws;

  if (ws_size < WS_NEED) {
    k_diag<<<(out_size + 255) / 256, 256, 0, stream>>>(out, out_size, (unsigned)(ws_size >> 20));
    return;
  }

  k_prep<<<3217, 256, 0, stream>>>(Wxi, Wxf, Wxo, Wxc, Whi, Whf, Who, Whc, bi, bfv, bo, bc, ws);
  k_embed<<<512, 256, 0, stream>>>(ids, emb, ws);
  k_lstm<<<256, 256, 0, stream>>>(ws);
  k_final<<<128, 64, 0, stream>>>(ws, Whq, bq, out);
}